// Round 19
// baseline (2203.164 us; speedup 1.0000x reference)
//
#include <hip/hip_runtime.h>

// SNN: conv2d(3x3, same, no bias, Cin=Cout=64) + LIF scan (tau=2, v_th=1, hard reset)
// Numerics contract (R13, PASS R14/R15/R16/R18):
//   conv: f32, SINGLE FMA chain per output in flat (ci, ky, kx) order g=ci*9+k
//   scan: float64, v' = v + (z - v)*0.5, spike = v' >= 1.0, hard reset to 0.
// R19 mechanism fix: R16/R18 proved the compiler scalarizes any weight load
// with a wave-uniform address into s_load (SMEM). On gfx9 SMEM and LDS share
// lgkmcnt and complete out-of-order -> the ds_read(nb) + s_load(weights) mix
// forces lgkmcnt(0) full drains every step -> VALUBusy 23%, 2.2ms.
// Fix: add a divergent-looking zero (loaded from LDS; un-foldable) to the
// weight index -> compiler must emit per-lane global_load_dwordx4 (VMEM,
// vmcnt-tracked, pipelined, decoupled from LDS traffic). Values identical.

#define T_STEPS 8
#define BATCH   16
#define CIN     64
#define COUT    64
#define IMH     64
#define IMW     64
#define HW      (IMH * IMW)
#define X_ELEMS (T_STEPS * BATCH * CIN * HW)   // 33,554,432
#define W_ELEMS (COUT * CIN * 9)               // 36,864

// [co][g] -> [g][co]: per (ci,k) step, a wave's 16 weights are one contiguous
// 64B block (float4-loadable, L2-hot).
__global__ void transpose_weights(const float* __restrict__ wf, float* __restrict__ wt) {
    int i = blockIdx.x * 256 + threadIdx.x;     // i = co*576 + g
    if (i < W_ELEMS) {
        int co = i / 576;
        int g  = i - co * 576;
        wt[g * 64 + co] = wf[i];
    }
}

__device__ __forceinline__ float stage_load(const float* xim, int h0, int w0,
                                            int q) {
    int ci  = q / 100;
    int rem = q - ci * 100;
    int hh  = rem / 10;
    int wl  = rem - hh * 10;
    int gh  = h0 - 1 + hh;
    int gw  = w0 - 1 + wl;
    float val = 0.0f;
    if ((unsigned)gh < IMH && (unsigned)gw < IMW)
        val = xim[ci * HW + gh * IMW + gw];
    return val;
}

__global__ __launch_bounds__(256, 2)
void snn_conv_lif_f0(const float* __restrict__ x, const float* __restrict__ wt,
                     float* __restrict__ out) {
    __shared__ float xt[CIN][10][12];   // stride 12: conv reads worst 2-way (free)
    __shared__ int   s_zero;            // divergence seed (always 0)

    const int tid  = threadIdx.x;
    const int lane = tid & 63;
    const int wid  = __builtin_amdgcn_readfirstlane(tid >> 6);

    if (tid == 0) s_zero = 0;           // published by the t-loop's first barrier

    const int b    = blockIdx.x >> 6;        // 0..15
    const int tile = blockIdx.x & 63;        // 64 tiles of 8x8
    const int h0   = (tile >> 3) << 3;
    const int w0   = (tile & 7) << 3;
    const int ph   = lane >> 3;
    const int pw   = lane & 7;
    const int cobase = wid << 4;             // 16 c_out per wave
    const int oh = h0 + ph, ow = w0 + pw;

    double v[16];                            // f64 LIF state
#pragma unroll
    for (int i = 0; i < 16; ++i) v[i] = 0.0;

    // prefetch t=0 staging values into registers
    float r[25];
    {
        const float* xim = x + (size_t)b * CIN * HW;
#pragma unroll
        for (int j = 0; j < 25; ++j)
            r[j] = stage_load(xim, h0, w0, tid + j * 256);
    }

    for (int t = 0; t < T_STEPS; ++t) {
        __syncthreads();                     // prior compute done reading xt
        // ---- write staged regs to (padded) LDS ----
#pragma unroll
        for (int j = 0; j < 25; ++j) {
            int q   = tid + j * 256;         // 0..6399
            int ci  = q / 100;
            int rem = q - ci * 100;
            int hh  = rem / 10;
            int wl  = rem - hh * 10;
            xt[ci][hh][wl] = r[j];
        }
        __syncthreads();

        // divergent-looking zero: compiler cannot prove uniformity of an LDS
        // load -> weight addresses below become per-lane -> VMEM loads.
        const int zz = s_zero;

        // ---- issue t+1 prefetch; HBM latency hides under the conv below ----
        if (t + 1 < T_STEPS) {
            const float* xim = x + (size_t)((t + 1) * BATCH + b) * CIN * HW;
#pragma unroll
            for (int j = 0; j < 25; ++j)
                r[j] = stage_load(xim, h0, w0, tid + j * 256);
        }

        // ---- conv: per c_out, ONE sequential FMA chain over g = ci*9+k ----
        float z[16];
#pragma unroll
        for (int i = 0; i < 16; ++i) z[i] = 0.0f;

        for (int ci = 0; ci < CIN; ++ci) {
            float nb[9];
#pragma unroll
            for (int dy = 0; dy < 3; ++dy)
#pragma unroll
                for (int dx = 0; dx < 3; ++dx)
                    nb[dy * 3 + dx] = xt[ci][ph + dy][pw + dx];

#pragma unroll
            for (int k = 0; k < 9; ++k) {
                float xv = nb[k];
                const float4* w4 = (const float4*)(wt + (ci * 9 + k) * 64 + cobase + zz);
                float4 wa = w4[0], wb = w4[1], wc = w4[2], wd = w4[3];
                z[0]  = __builtin_fmaf(wa.x, xv, z[0]);
                z[1]  = __builtin_fmaf(wa.y, xv, z[1]);
                z[2]  = __builtin_fmaf(wa.z, xv, z[2]);
                z[3]  = __builtin_fmaf(wa.w, xv, z[3]);
                z[4]  = __builtin_fmaf(wb.x, xv, z[4]);
                z[5]  = __builtin_fmaf(wb.y, xv, z[5]);
                z[6]  = __builtin_fmaf(wb.z, xv, z[6]);
                z[7]  = __builtin_fmaf(wb.w, xv, z[7]);
                z[8]  = __builtin_fmaf(wc.x, xv, z[8]);
                z[9]  = __builtin_fmaf(wc.y, xv, z[9]);
                z[10] = __builtin_fmaf(wc.z, xv, z[10]);
                z[11] = __builtin_fmaf(wc.w, xv, z[11]);
                z[12] = __builtin_fmaf(wd.x, xv, z[12]);
                z[13] = __builtin_fmaf(wd.y, xv, z[13]);
                z[14] = __builtin_fmaf(wd.z, xv, z[14]);
                z[15] = __builtin_fmaf(wd.w, xv, z[15]);
            }
        }

        // ---- f64 LIF scan ----
        size_t obase = ((size_t)(t * BATCH + b) * COUT + cobase) * HW
                     + (size_t)oh * IMW + ow;
#pragma unroll
        for (int i = 0; i < 16; ++i) {
            double d  = (double)z[i] - v[i];
            double nv = v[i] + d * 0.5;
            bool  sp  = (nv >= 1.0);
            out[obase + (size_t)i * HW] = sp ? 1.0f : 0.0f;
            v[i] = sp ? 0.0 : nv;
        }
    }
}

// Fallback without workspace: identical numerics, strided weight reads.
__global__ __launch_bounds__(256)
void snn_conv_lif_f0_direct(const float* __restrict__ x, const float* __restrict__ cw,
                            float* __restrict__ out) {
    __shared__ float xt[CIN][10][12];

    const int tid  = threadIdx.x;
    const int lane = tid & 63;
    const int wid  = __builtin_amdgcn_readfirstlane(tid >> 6);
    const int b    = blockIdx.x >> 6;
    const int tile = blockIdx.x & 63;
    const int h0   = (tile >> 3) << 3;
    const int w0   = (tile & 7) << 3;
    const int ph   = lane >> 3, pw = lane & 7;
    const int cobase = wid << 4;
    const int oh = h0 + ph, ow = w0 + pw;

    double v[16];
#pragma unroll
    for (int i = 0; i < 16; ++i) v[i] = 0.0;

    for (int t = 0; t < T_STEPS; ++t) {
        __syncthreads();
        const float* xim = x + (size_t)(t * BATCH + b) * CIN * HW;
#pragma unroll
        for (int j = 0; j < 25; ++j) {
            int q   = tid + j * 256;
            int ci  = q / 100;
            int rem = q - ci * 100;
            int hh  = rem / 10;
            int wl  = rem - hh * 10;
            xt[ci][hh][wl] = stage_load(xim, h0, w0, q);
        }
        __syncthreads();

        float z[16];
#pragma unroll
        for (int i = 0; i < 16; ++i) z[i] = 0.0f;

        for (int ci = 0; ci < CIN; ++ci) {
            float nb[9];
#pragma unroll
            for (int dy = 0; dy < 3; ++dy)
#pragma unroll
                for (int dx = 0; dx < 3; ++dx)
                    nb[dy * 3 + dx] = xt[ci][ph + dy][pw + dx];
            const float* wp = cw + ci * 9;
#pragma unroll
            for (int k = 0; k < 9; ++k) {
                float xv = nb[k];
#pragma unroll
                for (int i = 0; i < 16; ++i)
                    z[i] = __builtin_fmaf(wp[(cobase + i) * (CIN * 9) + k], xv, z[i]);
            }
        }

        size_t obase = ((size_t)(t * BATCH + b) * COUT + cobase) * HW
                     + (size_t)oh * IMW + ow;
#pragma unroll
        for (int i = 0; i < 16; ++i) {
            double d  = (double)z[i] - v[i];
            double nv = v[i] + d * 0.5;
            bool  sp  = (nv >= 1.0);
            out[obase + (size_t)i * HW] = sp ? 1.0f : 0.0f;
            v[i] = sp ? 0.0 : nv;
        }
    }
}

extern "C" void kernel_launch(void* const* d_in, const int* in_sizes, int n_in,
                              void* d_out, int out_size, void* d_ws, size_t ws_size,
                              hipStream_t stream) {
    // Resolve inputs by size: x = 33.5M elems, conv_w = 36864.
    const float* x  = (const float*)d_in[0];
    const float* wf = (const float*)d_in[1];
    if (n_in >= 2) {
        if (in_sizes[0] == W_ELEMS || in_sizes[1] == X_ELEMS) {
            x  = (const float*)d_in[1];
            wf = (const float*)d_in[0];
        }
    }
    float* out = (float*)d_out;
    (void)out_size;

    dim3 grid(BATCH * 64);
    dim3 block(256);

    if (ws_size >= (size_t)W_ELEMS * sizeof(float)) {
        float* wt = (float*)d_ws;
        hipLaunchKernelGGL(transpose_weights, dim3((W_ELEMS + 255) / 256), block, 0, stream, wf, wt);
        hipLaunchKernelGGL(snn_conv_lif_f0, grid, block, 0, stream, x, wt, out);
    } else {
        hipLaunchKernelGGL(snn_conv_lif_f0_direct, grid, block, 0, stream, x, wf, out);
    }
}

// Round 20
// 527.065 us; speedup vs baseline: 4.1801x; 4.1801x over previous
//
#include <hip/hip_runtime.h>

// SNN: conv2d(3x3, same, no bias, Cin=Cout=64) + LIF scan (tau=2, v_th=1, hard reset)
// Numerics contract (R13, verified PASS in R14):
//   conv: f32, SINGLE FMA chain per output in flat (ci, ky, kx) order g=ci*9+k
//   scan: float64, v' = v + (z - v)*0.5, spike = v' >= 1.0, hard reset to 0.
// R20 = EXACT revert to R15, the measured champion (528us bench / 592us steady):
//   - LDS row stride 12 (read conflicts 2-way max = free)
//   - T14 async-STAGE: t+1's 25 global loads issued into regs under the conv
//   - float4 weight loads, __launch_bounds__(256,4) (VGPR 64; known ~25-reg
//     spill is the lesser evil -- every attempt to lift it (R16-R19) landed in
//     a scalarized-SMEM scheduling regime at 2.2ms or failed replay).

#define T_STEPS 8
#define BATCH   16
#define CIN     64
#define COUT    64
#define IMH     64
#define IMW     64
#define HW      (IMH * IMW)
#define X_ELEMS (T_STEPS * BATCH * CIN * HW)   // 33,554,432
#define W_ELEMS (COUT * CIN * 9)               // 36,864

// [co][g] -> [g][co]: per (ci,k) step, a wave's 16 weights are one contiguous
// 64B block (float4-loadable, L2-hot).
__global__ void transpose_weights(const float* __restrict__ wf, float* __restrict__ wt) {
    int i = blockIdx.x * 256 + threadIdx.x;     // i = co*576 + g
    if (i < W_ELEMS) {
        int co = i / 576;
        int g  = i - co * 576;
        wt[g * 64 + co] = wf[i];
    }
}

__device__ __forceinline__ float stage_load(const float* xim, int h0, int w0,
                                            int q) {
    int ci  = q / 100;
    int rem = q - ci * 100;
    int hh  = rem / 10;
    int wl  = rem - hh * 10;
    int gh  = h0 - 1 + hh;
    int gw  = w0 - 1 + wl;
    float val = 0.0f;
    if ((unsigned)gh < IMH && (unsigned)gw < IMW)
        val = xim[ci * HW + gh * IMW + gw];
    return val;
}

__global__ __launch_bounds__(256, 4)
void snn_conv_lif_f0(const float* __restrict__ x, const float* __restrict__ wt,
                     float* __restrict__ out) {
    __shared__ float xt[CIN][10][12];   // padded stride 12: 30.7 KB

    const int tid  = threadIdx.x;
    const int lane = tid & 63;
    const int wid  = __builtin_amdgcn_readfirstlane(tid >> 6);

    const int b    = blockIdx.x >> 6;        // 0..15
    const int tile = blockIdx.x & 63;        // 64 tiles of 8x8
    const int h0   = (tile >> 3) << 3;
    const int w0   = (tile & 7) << 3;
    const int ph   = lane >> 3;
    const int pw   = lane & 7;
    const int cobase = wid << 4;             // 16 c_out per wave
    const int oh = h0 + ph, ow = w0 + pw;

    double v[16];                            // f64 LIF state
#pragma unroll
    for (int i = 0; i < 16; ++i) v[i] = 0.0;

    // prefetch t=0 staging values into registers
    float r[25];
    {
        const float* xim = x + (size_t)b * CIN * HW;
#pragma unroll
        for (int j = 0; j < 25; ++j)
            r[j] = stage_load(xim, h0, w0, tid + j * 256);
    }

    for (int t = 0; t < T_STEPS; ++t) {
        __syncthreads();                     // prior compute done reading xt
        // ---- write staged regs to (padded) LDS ----
#pragma unroll
        for (int j = 0; j < 25; ++j) {
            int q   = tid + j * 256;         // 0..6399
            int ci  = q / 100;
            int rem = q - ci * 100;
            int hh  = rem / 10;
            int wl  = rem - hh * 10;
            xt[ci][hh][wl] = r[j];
        }
        __syncthreads();

        // ---- issue t+1 prefetch; HBM latency hides under the conv below ----
        if (t + 1 < T_STEPS) {
            const float* xim = x + (size_t)((t + 1) * BATCH + b) * CIN * HW;
#pragma unroll
            for (int j = 0; j < 25; ++j)
                r[j] = stage_load(xim, h0, w0, tid + j * 256);
        }

        // ---- conv: per c_out, ONE sequential FMA chain over g = ci*9+k ----
        float z[16];
#pragma unroll
        for (int i = 0; i < 16; ++i) z[i] = 0.0f;

        for (int ci = 0; ci < CIN; ++ci) {
            float nb[9];
#pragma unroll
            for (int dy = 0; dy < 3; ++dy)
#pragma unroll
                for (int dx = 0; dx < 3; ++dx)
                    nb[dy * 3 + dx] = xt[ci][ph + dy][pw + dx];

#pragma unroll
            for (int k = 0; k < 9; ++k) {
                float xv = nb[k];
                const float4* w4 = (const float4*)(wt + (ci * 9 + k) * 64 + cobase);
                float4 wa = w4[0], wb = w4[1], wc = w4[2], wd = w4[3];
                z[0]  = __builtin_fmaf(wa.x, xv, z[0]);
                z[1]  = __builtin_fmaf(wa.y, xv, z[1]);
                z[2]  = __builtin_fmaf(wa.z, xv, z[2]);
                z[3]  = __builtin_fmaf(wa.w, xv, z[3]);
                z[4]  = __builtin_fmaf(wb.x, xv, z[4]);
                z[5]  = __builtin_fmaf(wb.y, xv, z[5]);
                z[6]  = __builtin_fmaf(wb.z, xv, z[6]);
                z[7]  = __builtin_fmaf(wb.w, xv, z[7]);
                z[8]  = __builtin_fmaf(wc.x, xv, z[8]);
                z[9]  = __builtin_fmaf(wc.y, xv, z[9]);
                z[10] = __builtin_fmaf(wc.z, xv, z[10]);
                z[11] = __builtin_fmaf(wc.w, xv, z[11]);
                z[12] = __builtin_fmaf(wd.x, xv, z[12]);
                z[13] = __builtin_fmaf(wd.y, xv, z[13]);
                z[14] = __builtin_fmaf(wd.z, xv, z[14]);
                z[15] = __builtin_fmaf(wd.w, xv, z[15]);
            }
        }

        // ---- f64 LIF scan ----
        size_t obase = ((size_t)(t * BATCH + b) * COUT + cobase) * HW
                     + (size_t)oh * IMW + ow;
#pragma unroll
        for (int i = 0; i < 16; ++i) {
            double d  = (double)z[i] - v[i];
            double nv = v[i] + d * 0.5;
            bool  sp  = (nv >= 1.0);
            out[obase + (size_t)i * HW] = sp ? 1.0f : 0.0f;
            v[i] = sp ? 0.0 : nv;
        }
    }
}

// Fallback without workspace: identical numerics, strided weight reads.
__global__ __launch_bounds__(256)
void snn_conv_lif_f0_direct(const float* __restrict__ x, const float* __restrict__ cw,
                            float* __restrict__ out) {
    __shared__ float xt[CIN][10][12];

    const int tid  = threadIdx.x;
    const int lane = tid & 63;
    const int wid  = __builtin_amdgcn_readfirstlane(tid >> 6);
    const int b    = blockIdx.x >> 6;
    const int tile = blockIdx.x & 63;
    const int h0   = (tile >> 3) << 3;
    const int w0   = (tile & 7) << 3;
    const int ph   = lane >> 3, pw = lane & 7;
    const int cobase = wid << 4;
    const int oh = h0 + ph, ow = w0 + pw;

    double v[16];
#pragma unroll
    for (int i = 0; i < 16; ++i) v[i] = 0.0;

    for (int t = 0; t < T_STEPS; ++t) {
        __syncthreads();
        const float* xim = x + (size_t)(t * BATCH + b) * CIN * HW;
#pragma unroll
        for (int j = 0; j < 25; ++j) {
            int q   = tid + j * 256;
            int ci  = q / 100;
            int rem = q - ci * 100;
            int hh  = rem / 10;
            int wl  = rem - hh * 10;
            xt[ci][hh][wl] = stage_load(xim, h0, w0, q);
        }
        __syncthreads();

        float z[16];
#pragma unroll
        for (int i = 0; i < 16; ++i) z[i] = 0.0f;

        for (int ci = 0; ci < CIN; ++ci) {
            float nb[9];
#pragma unroll
            for (int dy = 0; dy < 3; ++dy)
#pragma unroll
                for (int dx = 0; dx < 3; ++dx)
                    nb[dy * 3 + dx] = xt[ci][ph + dy][pw + dx];
            const float* wp = cw + ci * 9;
#pragma unroll
            for (int k = 0; k < 9; ++k) {
                float xv = nb[k];
#pragma unroll
                for (int i = 0; i < 16; ++i)
                    z[i] = __builtin_fmaf(wp[(cobase + i) * (CIN * 9) + k], xv, z[i]);
            }
        }

        size_t obase = ((size_t)(t * BATCH + b) * COUT + cobase) * HW
                     + (size_t)oh * IMW + ow;
#pragma unroll
        for (int i = 0; i < 16; ++i) {
            double d  = (double)z[i] - v[i];
            double nv = v[i] + d * 0.5;
            bool  sp  = (nv >= 1.0);
            out[obase + (size_t)i * HW] = sp ? 1.0f : 0.0f;
            v[i] = sp ? 0.0 : nv;
        }
    }
}

extern "C" void kernel_launch(void* const* d_in, const int* in_sizes, int n_in,
                              void* d_out, int out_size, void* d_ws, size_t ws_size,
                              hipStream_t stream) {
    // Resolve inputs by size: x = 33.5M elems, conv_w = 36864.
    const float* x  = (const float*)d_in[0];
    const float* wf = (const float*)d_in[1];
    if (n_in >= 2) {
        if (in_sizes[0] == W_ELEMS || in_sizes[1] == X_ELEMS) {
            x  = (const float*)d_in[1];
            wf = (const float*)d_in[0];
        }
    }
    float* out = (float*)d_out;
    (void)out_size;

    dim3 grid(BATCH * 64);
    dim3 block(256);

    if (ws_size >= (size_t)W_ELEMS * sizeof(float)) {
        float* wt = (float*)d_ws;
        hipLaunchKernelGGL(transpose_weights, dim3((W_ELEMS + 255) / 256), block, 0, stream, wf, wt);
        hipLaunchKernelGGL(snn_conv_lif_f0, grid, block, 0, stream, x, wt, out);
    } else {
        hipLaunchKernelGGL(snn_conv_lif_f0_direct, grid, block, 0, stream, x, wf, out);
    }
}